// Round 6
// baseline (7313.262 us; speedup 1.0000x reference)
//
#include <hip/hip_runtime.h>
#include <math.h>

// ---------------------------------------------------------------------------
// Hierarchical bi-GRU (char bi-GRU -> word bi-GRU -> FC head), fp32.
//
//   gates = sigmoid(x@Wg_x + h@Wg_h + bg)      (x-part precomputed)
//   c     = tanh  (x@Wc_x + (r*h)@Wc_h + bc)
//   h'    = mask ? u*h + (1-u)*c : h
//
// Persistent fused GRU per level: block owns R rows, h in LDS, T steps inside.
// NEW vs r5: rows sorted by length DESCENDING (stable counting sort) so blocks
// group similar lengths -> per-block early exit at max(len); u-gate kept in
// registers (thread owns col pair {2t,2t+1} for r-gate, u-gate and cand) ->
// LDS 50->33KB (char), 4 blocks/CU.
// ---------------------------------------------------------------------------

#define TILE 64
#define BKK 16

enum AMode { A_PLAIN = 0, A_CHARSTATE = 1, A_GATHER = 3 };
enum EMode { E_BIAS = 0, E_XW = 3 };

struct GemmArgs {
  int M, N, K;
  const float* A; int lda;
  const int*   arows;
  const float* B;
  const float* bias;
  const float* XT; int ldxt;
  const int*   cidx;
  float* Cout; int ldc;
};

__device__ __forceinline__ float sigmoidf_(float x) { return 1.0f / (1.0f + expf(-x)); }

template<int AM, int EM>
__global__ __launch_bounds__(256) void gemm_k(GemmArgs p) {
  __shared__ float As[BKK][TILE];
  __shared__ float Bs[BKK][TILE];
  const int tid = threadIdx.x;
  const int tx = tid & 15, ty = tid >> 4;
  const int m0 = blockIdx.y * TILE, n0 = blockIdx.x * TILE;
  const int la_r = tid >> 2, la_k = (tid & 3) << 2;
  const int lb_k = tid >> 4, lb_n = (tid & 15) << 2;

  float acc[4][4] = {};
  int arow = 0;
  if constexpr (AM == A_GATHER) arow = p.arows[m0 + la_r];

  for (int k0 = 0; k0 < p.K; k0 += BKK) {
    float4 av;
    const int m = m0 + la_r;
    const int k = k0 + la_k;
    if constexpr (AM == A_PLAIN) {
      av = *reinterpret_cast<const float4*>(p.A + (size_t)m * p.lda + k);
    } else if constexpr (AM == A_CHARSTATE) {
      const float* ap = (k < 512) ? (p.A + (size_t)m * 512 + k)
                                  : (p.A + (size_t)(2048 + m) * 512 + (k - 512));
      av = *reinterpret_cast<const float4*>(ap);
    } else { // A_GATHER
      av = *reinterpret_cast<const float4*>(p.A + (size_t)arow * p.lda + k);
    }
    As[la_k + 0][la_r] = av.x;
    As[la_k + 1][la_r] = av.y;
    As[la_k + 2][la_r] = av.z;
    As[la_k + 3][la_r] = av.w;
    float4 bv = *reinterpret_cast<const float4*>(p.B + (size_t)(k0 + lb_k) * p.N + n0 + lb_n);
    *reinterpret_cast<float4*>(&Bs[lb_k][lb_n]) = bv;
    __syncthreads();
#pragma unroll
    for (int kk = 0; kk < BKK; ++kk) {
      float4 a = *reinterpret_cast<const float4*>(&As[kk][ty << 2]);
      float4 b = *reinterpret_cast<const float4*>(&Bs[kk][tx << 2]);
      acc[0][0] += a.x * b.x; acc[0][1] += a.x * b.y; acc[0][2] += a.x * b.z; acc[0][3] += a.x * b.w;
      acc[1][0] += a.y * b.x; acc[1][1] += a.y * b.y; acc[1][2] += a.y * b.z; acc[1][3] += a.y * b.w;
      acc[2][0] += a.z * b.x; acc[2][1] += a.z * b.y; acc[2][2] += a.z * b.z; acc[2][3] += a.z * b.w;
      acc[3][0] += a.w * b.x; acc[3][1] += a.w * b.y; acc[3][2] += a.w * b.z; acc[3][3] += a.w * b.w;
    }
    __syncthreads();
  }

  const int rbase = m0 + (ty << 2);
  const int cbase = n0 + (tx << 2);
#pragma unroll
  for (int i = 0; i < 4; ++i) {
    const int row = rbase + i;
    if constexpr (EM == E_BIAS) {
#pragma unroll
      for (int j = 0; j < 4; ++j) {
        const int col = cbase + j;
        p.Cout[(size_t)row * p.ldc + col] = acc[i][j] + p.bias[col];
      }
    } else { // E_XW
      const int cs = p.cidx[row];
      const float* xrow = p.XT + (size_t)cs * p.ldxt;
#pragma unroll
      for (int j = 0; j < 4; ++j) {
        const int col = cbase + j;
        p.Cout[(size_t)row * p.ldc + col] = acc[i][j] + xrow[col];
      }
    }
  }
}

// ---------------------------------------------------------------------------
// Stable counting sort by length, DESCENDING. sidx[rank] = original row.
// Deterministic: rank = #{len > L} + #{j < i : len[j] == L}.
// ---------------------------------------------------------------------------
template<int N, int MAXL>
__global__ __launch_bounds__(256) void sort_len_k(const int* __restrict__ lens,
                                                  int* __restrict__ sidx) {
  __shared__ int l_s[N];
  __shared__ int hist[MAXL + 1];
  __shared__ int pref[MAXL + 1];
  const int tid = threadIdx.x;
  for (int i = tid; i < N; i += 256) l_s[i] = lens[i];
  for (int i = tid; i <= MAXL; i += 256) hist[i] = 0;
  __syncthreads();
  for (int i = tid; i < N; i += 256) atomicAdd(&hist[l_s[i]], 1);
  __syncthreads();
  if (tid == 0) {
    pref[MAXL] = 0;
    for (int L = MAXL - 1; L >= 0; --L) pref[L] = pref[L + 1] + hist[L + 1];
  }
  __syncthreads();
  for (int i = tid; i < N; i += 256) {
    const int L = l_s[i];
    int c = 0;
    for (int j = 0; j < i; ++j) c += (l_s[j] == L) ? 1 : 0;
    sidx[pref[L] + c] = i;
  }
}

// ---------------------------------------------------------------------------
// Persistent fused GRU, length-sorted rows + early exit + u-in-registers.
// Thread t owns cols {2t,2t+1}: r-gate at 2t, u-gate at 512+2t, cand at 2t.
// Grid: 2*G blocks (G = NU/R); first G = forward, rest = backward.
// ---------------------------------------------------------------------------
template<int R, int NU, int TT, bool CHARMODE>
__global__ __launch_bounds__(256) void gru_fused(
    const float* __restrict__ Whg,   // [512,1024]
    const float* __restrict__ Whc,   // [512,512]
    const float* __restrict__ Xg,    // x-part gate table
    const float* __restrict__ Xc,    // x-part cand table
    const int*   __restrict__ lens,  // [NU]
    const int*   __restrict__ seqs,  // CHARMODE: [NU,TT]
    const int*   __restrict__ sidx,  // [NU] length-sorted row ids
    float* __restrict__ Hout)        // [2*NU, 512]
{
  __shared__ float h_s [R][512];
  __shared__ float rh_s[R][512];
  __shared__ int   seq_s[CHARMODE ? R * TT : 1];
  __shared__ int   us_s[R];
  __shared__ int   len_s[R];
  __shared__ int   xog_s[R];
  __shared__ int   xoc_s[R];
  __shared__ int   msk_s[R];
  __shared__ int   maxlen_s;

  const int tid = threadIdx.x;
  const int G   = NU / R;
  const bool bw = blockIdx.x >= G;
  const int g   = bw ? (blockIdx.x - G) : blockIdx.x;

  if (tid < R) {
    const int us = sidx[g * R + tid];
    us_s[tid]  = us;
    len_s[tid] = lens[us];
  }
  __syncthreads();
  for (int i = tid; i < R * 512; i += 256) h_s[i >> 9][i & 511] = 0.0f;
  if constexpr (CHARMODE) {
    for (int i = tid; i < R * TT; i += 256)
      seq_s[i] = seqs[(size_t)us_s[i / TT] * TT + (i % TT)];
  }
  if (tid == 0) {
    int m = 0;
#pragma unroll
    for (int i = 0; i < R; ++i) m = len_s[i] > m ? len_s[i] : m;
    maxlen_s = m;
  }
  __syncthreads();

  const int cg = tid << 1;  // owned col pair

  float2 u_reg[R];

  for (int t = 0; t < TT; ++t) {
    if (t >= maxlen_s) break;   // uniform: all rows in block frozen from here

    if (tid < R) {
      const int L = len_s[tid];
      int pos = bw ? (L - 1 - t) : t;
      pos = pos < 0 ? 0 : (pos > TT - 1 ? TT - 1 : pos);
      int xr;
      if constexpr (CHARMODE) xr = seq_s[tid * TT + pos];
      else                    xr = us_s[tid] * TT + pos;
      xog_s[tid] = xr * 1024;
      xoc_s[tid] = xr * 512;
      msk_s[tid] = (t < L) ? 1 : 0;
    }
    __syncthreads();

    // ---- phase 1: gates; rh -> LDS, u -> registers ----
    float2 ar[R], au[R];
#pragma unroll
    for (int r = 0; r < R; ++r) { ar[r] = make_float2(0.f, 0.f); au[r] = make_float2(0.f, 0.f); }
#pragma unroll 8
    for (int k = 0; k < 512; ++k) {
      const float2 wr = *reinterpret_cast<const float2*>(Whg + (size_t)k * 1024 + cg);
      const float2 wu = *reinterpret_cast<const float2*>(Whg + (size_t)k * 1024 + 512 + cg);
#pragma unroll
      for (int r = 0; r < R; ++r) {
        const float hv = h_s[r][k];
        ar[r].x += hv * wr.x; ar[r].y += hv * wr.y;
        au[r].x += hv * wu.x; au[r].y += hv * wu.y;
      }
    }
#pragma unroll
    for (int r = 0; r < R; ++r) {
      const float2 xgr = *reinterpret_cast<const float2*>(Xg + xog_s[r] + cg);
      const float2 xgu = *reinterpret_cast<const float2*>(Xg + xog_s[r] + 512 + cg);
      const float rgx = sigmoidf_(ar[r].x + xgr.x);
      const float rgy = sigmoidf_(ar[r].y + xgr.y);
      u_reg[r].x = sigmoidf_(au[r].x + xgu.x);
      u_reg[r].y = sigmoidf_(au[r].y + xgu.y);
      rh_s[r][cg + 0] = rgx * h_s[r][cg + 0];
      rh_s[r][cg + 1] = rgy * h_s[r][cg + 1];
    }
    __syncthreads();

    // ---- phase 2: cand + state update ----
    float2 ac[R];
#pragma unroll
    for (int r = 0; r < R; ++r) ac[r] = make_float2(0.f, 0.f);
#pragma unroll 8
    for (int k = 0; k < 512; ++k) {
      const float2 wc = *reinterpret_cast<const float2*>(Whc + (size_t)k * 512 + cg);
#pragma unroll
      for (int r = 0; r < R; ++r) {
        const float rv = rh_s[r][k];
        ac[r].x += rv * wc.x; ac[r].y += rv * wc.y;
      }
    }
#pragma unroll
    for (int r = 0; r < R; ++r) {
      const float2 xc = *reinterpret_cast<const float2*>(Xc + xoc_s[r] + cg);
      const float cx = tanhf(ac[r].x + xc.x);
      const float cy = tanhf(ac[r].y + xc.y);
      if (msk_s[r]) {
        const float ux = u_reg[r].x, uy = u_reg[r].y;
        const float hx = h_s[r][cg + 0], hy = h_s[r][cg + 1];
        h_s[r][cg + 0] = ux * hx + (1.0f - ux) * cx;
        h_s[r][cg + 1] = uy * hy + (1.0f - uy) * cy;
      }
    }
    __syncthreads();
  }

  for (int i = tid; i < R * 512; i += 256)
    Hout[(size_t)(us_s[i >> 9] + (bw ? NU : 0)) * 512 + (i & 511)] = h_s[i >> 9][i & 511];
}

// FC head
__global__ __launch_bounds__(64) void head_k(const float* __restrict__ Hw,
                                             const float* __restrict__ W1,
                                             const float* __restrict__ b1,
                                             const float* __restrict__ W2,
                                             const float* __restrict__ b2,
                                             float* __restrict__ out) {
  __shared__ float s[1024];
  __shared__ float hid[64];
  const int b = blockIdx.x;
  const int tid = threadIdx.x;
  for (int k = tid; k < 512; k += 64) {
    s[k]       = Hw[(size_t)b * 512 + k];
    s[512 + k] = Hw[(size_t)(256 + b) * 512 + k];
  }
  __syncthreads();
  float acc = b1[tid];
  for (int k = 0; k < 1024; ++k) acc += s[k] * W1[k * 64 + tid];
  acc = acc > 0.0f ? acc : 0.2f * acc;
  hid[tid] = acc;
  __syncthreads();
  if (tid < 2) {
    float a = b2[tid];
    for (int k = 0; k < 64; ++k) a += hid[k] * W2[k * 2 + tid];
    out[b * 2 + tid] = a;
  }
}

extern "C" void kernel_launch(void* const* d_in, const int* in_sizes, int n_in,
                              void* d_out, int out_size, void* d_ws, size_t ws_size,
                              hipStream_t stream) {
  const int*   charseqs      = (const int*)d_in[0];
  const int*   charseq_lens  = (const int*)d_in[1];
  const int*   charseq_ids   = (const int*)d_in[2];
  const int*   word_ids      = (const int*)d_in[3];
  const int*   sentence_lens = (const int*)d_in[4];
  const float* char_emb      = (const float*)d_in[5];
  const float* word_emb      = (const float*)d_in[6];
  const float* Wg_c          = (const float*)d_in[7];
  const float* bg_c          = (const float*)d_in[8];
  const float* Wc_c          = (const float*)d_in[9];
  const float* bc_c          = (const float*)d_in[10];
  const float* Wg_w          = (const float*)d_in[11];
  const float* bg_w          = (const float*)d_in[12];
  const float* Wc_w          = (const float*)d_in[13];
  const float* bc_w          = (const float*)d_in[14];
  const float* W1            = (const float*)d_in[15];
  const float* b1            = (const float*)d_in[16];
  const float* W2            = (const float*)d_in[17];
  const float* b2            = (const float*)d_in[18];
  float* out = (float*)d_out;

  float* ws = (float*)d_ws;
  size_t off = 0;
  auto alloc = [&](size_t n) { float* p = ws + off; off += n; return p; };
  float* XTABg = alloc(256 * 1024);
  float* XTABc = alloc(256 * 512);
  float* Hc    = alloc((size_t)4096 * 512);
  float* CTABg = alloc((size_t)2048 * 1024);
  float* CTABc = alloc((size_t)2048 * 512);
  float* XWg   = alloc((size_t)16384 * 1024);
  float* XWc   = alloc((size_t)16384 * 512);
  float* Hw    = alloc(512 * 512);
  int* sidx_c  = (int*)alloc(2048);
  int* sidx_w  = (int*)alloc(256);

  // --- Stage 0: length sorts (descending, stable, deterministic) ---
  sort_len_k<2048, 16><<<1, 256, 0, stream>>>(charseq_lens, sidx_c);
  sort_len_k<256, 64><<<1, 256, 0, stream>>>(sentence_lens, sidx_w);

  // --- Stage A: char x-part tables  [256,128]@[128,1536] ---
  {
    GemmArgs a{}; a.M = 256; a.N = 1024; a.K = 128;
    a.A = char_emb; a.lda = 128; a.B = Wg_c; a.bias = bg_c; a.Cout = XTABg; a.ldc = 1024;
    gemm_k<A_PLAIN, E_BIAS><<<dim3(1024 / TILE, 256 / TILE), 256, 0, stream>>>(a);
    GemmArgs c{}; c.M = 256; c.N = 512; c.K = 128;
    c.A = char_emb; c.lda = 128; c.B = Wc_c; c.bias = bc_c; c.Cout = XTABc; c.ldc = 512;
    gemm_k<A_PLAIN, E_BIAS><<<dim3(512 / TILE, 256 / TILE), 256, 0, stream>>>(c);
  }

  // --- Stage B: fused char bi-GRU (R=8 -> 512 blocks, 4 blocks/CU) ---
  gru_fused<8, 2048, 16, true><<<512, 256, 0, stream>>>(
      Wg_c + 128 * 1024, Wc_c + 128 * 512, XTABg, XTABc,
      charseq_lens, charseqs, sidx_c, Hc);

  // --- Stage C: per-wordform x-part of word GRU  [2048,1024]@[1024,1536] ---
  {
    GemmArgs a{}; a.M = 2048; a.N = 1024; a.K = 1024;
    a.A = Hc; a.B = Wg_w; a.bias = bg_w; a.Cout = CTABg; a.ldc = 1024;
    gemm_k<A_CHARSTATE, E_BIAS><<<dim3(1024 / TILE, 2048 / TILE), 256, 0, stream>>>(a);
    GemmArgs c{}; c.M = 2048; c.N = 512; c.K = 1024;
    c.A = Hc; c.B = Wc_w; c.bias = bc_w; c.Cout = CTABc; c.ldc = 512;
    gemm_k<A_CHARSTATE, E_BIAS><<<dim3(512 / TILE, 2048 / TILE), 256, 0, stream>>>(c);
  }

  // --- Stage D: word-emb x-part + CTAB gather  [16384,256]@[256,1536] ---
  {
    GemmArgs a{}; a.M = 16384; a.N = 1024; a.K = 256;
    a.A = word_emb; a.lda = 256; a.arows = word_ids; a.B = Wg_w + (size_t)1024 * 1024;
    a.XT = CTABg; a.ldxt = 1024; a.cidx = charseq_ids; a.Cout = XWg; a.ldc = 1024;
    gemm_k<A_GATHER, E_XW><<<dim3(1024 / TILE, 16384 / TILE), 256, 0, stream>>>(a);
    GemmArgs c{}; c.M = 16384; c.N = 512; c.K = 256;
    c.A = word_emb; c.lda = 256; c.arows = word_ids; c.B = Wc_w + (size_t)1024 * 512;
    c.XT = CTABc; c.ldxt = 512; c.cidx = charseq_ids; c.Cout = XWc; c.ldc = 512;
    gemm_k<A_GATHER, E_XW><<<dim3(512 / TILE, 16384 / TILE), 256, 0, stream>>>(c);
  }

  // --- Stage E: fused word bi-GRU (R=2 -> 256 blocks) ---
  gru_fused<2, 256, 64, false><<<256, 256, 0, stream>>>(
      Wg_w + (size_t)1280 * 1024, Wc_w + (size_t)1280 * 512, XWg, XWc,
      sentence_lens, nullptr, sidx_w, Hw);

  // --- Stage F: FC head ---
  head_k<<<256, 64, 0, stream>>>(Hw, W1, b1, W2, b2, out);
}